// Round 12
// baseline (179.857 us; speedup 1.0000x reference)
//
#include <hip/hip_runtime.h>

// Chambolle-Pock anisotropic TV prox. B=8, H=W=256, 200 iters, fp32.
//
// Round 27 (session r12): 2 BLOCKS/CU TO OVERLAP THE BARRIER STALL.
// r11 win confirmed exchange-latency theory (132.6->121.5us, bit-equal
// absmax). Residual: wall 1458 = 960 busy + ~500 all-wave stall
// (barrier convergence + LDS round trip + chain tail; 1 block/CU means
// nothing issues during it). r1's "blocks don't help" was the OLD
// LDS-pipe-contended structure; here LDS is ~idle -> retest.
// Change: 8 waves x RPW=7, region 56x64, RIr=32, grid 7x8x8=448
// -> 2 blocks/CU (16 waves/CU, 4/SIMD), independent barriers
// interleave. Busy +31% (halo redundancy 2.13->2.8x) traded against
// the 500cyc stall. Also: boundary-row ds_writes hoisted to right
// after ub[0]/ub[RPW-1] are produced (r11 mechanism, more lgkm slack).
// waves_per_eu(4,4): max=4 -> 128-reg budget, satisfiable for 8-wave
// block (r9 lesson inverted). Falsifier: ~160us + VALUBusy ~66% kills
// block-overlap; next lever would be issue-bloat via disasm.
// Carried (validated r8-r11): T=200 single launch, H=12 halo, lane=col
// DPP wave_shl/shr, in-register vertical, guard-row zero xb, parity
// dbuf + unroll 2, 1 barrier/iter, med3-bounded edge garbage,
// OOB loads -> 0, row<256 store guard.

#define Hc 256
#define Wc 256
#define Bc 8

constexpr int Tl  = 200;     // all iterations in one launch
constexpr int HLc = 12;      // halo width
constexpr int RIr = 32;      // interior rows per block (56 - 2*12)
constexpr int RIc = 40;      // interior cols per block (64 - 2*12)
constexpr int NW  = 8;       // waves per block (512 threads)
constexpr int RPW = 7;       // rows per wave (56 region rows / 8 waves)

constexpr float TAUc = 0.35355339f;
constexpr float SIGc = 0.35355339f;
constexpr float Ac_  = 1.0f / (1.0f + TAUc);
constexpr float Bq_  = TAUc * Ac_;

// clamp to [-b, b] in one v_med3_f32; NaN v -> -b (finite, 0 when b==0).
__device__ __forceinline__ float clipf(float v, float b) {
    return __builtin_amdgcn_fmed3f(v, -b, b);
}

// lane i <- lane i+1 (wave-wide); lane 63 -> 0.  WAVE_SHL1 = 0x130.
__device__ __forceinline__ float dpp_shl1(float x) {
    return __int_as_float(__builtin_amdgcn_update_dpp(
        0, __float_as_int(x), 0x130, 0xf, 0xf, true));
}
// lane i <- lane i-1 (wave-wide); lane 0 -> 0.  WAVE_SHR1 = 0x138.
__device__ __forceinline__ float dpp_shr1(float x) {
    return __int_as_float(__builtin_amdgcn_update_dpp(
        0, __float_as_int(x), 0x138, 0xf, 0xf, true));
}

__global__ __launch_bounds__(NW * 64)
__attribute__((amdgpu_waves_per_eu(4, 4)))
void tv_one(const float* __restrict__ f, const float* __restrict__ lam,
            float* __restrict__ fin_out)
{
    // parity-dbuf boundary-row exchange with ZERO GUARD ROWS:
    // wave w writes slot w+1; slots 0 and NW+1 stay zero forever.
    __shared__ float xb[2][NW + 2][2][64];

    const int t    = threadIdx.x;
    const int w    = t >> 6;          // wave 0..7 (row panel)
    const int lane = t & 63;          // region col
    const int tc   = blockIdx.x;      // 0..6
    const int tr   = blockIdx.y;      // 0..7
    const int b    = blockIdx.z;      // 0..7

    const int gi0 = tr * RIr - HLc;
    const int gj0 = tc * RIc - HLc;
    const int fr  = gi0 + w * RPW;    // first absolute row of this wave
    const int gj  = gj0 + lane;       // absolute col of this lane
    const bool colok = (unsigned)gj < 256u;
    const int boff = b * (Hc * Wc);

    float u[RPW], ub[RPW], p[RPW], q[RPW], bf[RPW], bp[RPW], bq[RPW];
    float pg, bpg;

    // ---- zero entire xb once (guards of both parities included) ----
    for (int idx = t; idx < 2 * (NW + 2) * 2 * 64; idx += NW * 64)
        ((float*)xb)[idx] = 0.f;

    // ---------------- load phase ----------------
    #pragma unroll
    for (int i = 0; i < RPW; ++i) {
        const int row = fr + i;
        const bool rok = colok && (unsigned)row < 256u;
        const float fv = rok ? f[boff + (row << 8) + gj] : 0.f;
        bf[i] = Bq_ * fv;
        u[i]  = fv;
        ub[i] = fv;
        p[i]  = 0.f;
        q[i]  = 0.f;
    }
    pg = 0.f;
    // bounds. p[i] pairs rows (fr+i, fr+i+1), bound lam[fr+i+1] (0 if pad).
    // q[i] pairs cols (gj, gj+1), bound lam[row][gj+1] (0 if pad).
    #pragma unroll
    for (int i = 0; i < RPW; ++i) {
        const int row = fr + i;
        bp[i] = (colok && row >= 0 && row + 1 <= 255)
                    ? lam[boff + ((row + 1) << 8) + gj] : 0.f;
        bq[i] = (colok && (unsigned)row < 256u && gj + 1 <= 255)
                    ? lam[boff + (row << 8) + gj + 1] : 0.f;
    }
    bpg = (colok && fr - 1 >= 0 && fr <= 255) ? lam[boff + (fr << 8) + gj] : 0.f;

    // ---------------- prologue write (buf 0) ----------------
    xb[0][w + 1][0][lane] = ub[0];
    xb[0][w + 1][1][lane] = ub[RPW - 1];
    __syncthreads();

    // ---------------- 200 iterations ----------------
    #pragma unroll 2
    for (int k = 0; k < Tl; ++k) {
        const int pb = k & 1;     // compile-time under unroll 2
        // raw reads (guard slots supply the 0 for w=0 / w=NW-1);
        // first consumer is the p-section — q-section covers latency.
        const float ubT = xb[pb][w][1][lane];
        const float ubB = xb[pb][w + 2][0][lane];

        // ---- q updates (uses prev-iter ub; right neighbor via DPP) ----
        #pragma unroll
        for (int i = 0; i < RPW; ++i) {
            const float ur = dpp_shl1(ub[i]);
            q[i] = clipf(fmaf(SIGc, ur - ub[i], q[i]), bq[i]);
        }
        // ---- p updates (vertical, in-register; panel edges via LDS) ----
        pg = clipf(fmaf(SIGc, ub[0] - ubT, pg), bpg);
        #pragma unroll
        for (int i = 0; i < RPW - 1; ++i)
            p[i] = clipf(fmaf(SIGc, ub[i + 1] - ub[i], p[i]), bp[i]);
        p[RPW - 1] = clipf(fmaf(SIGc, ubB - ub[RPW - 1], p[RPW - 1]), bp[RPW - 1]);

        const bool pub = (k != Tl - 1);

        // ---- u, ubar (left-neighbor q via DPP); boundary rows FIRST,
        //      each published to LDS immediately (max lgkm slack) ----
        {   // i = 0
            const float ql    = dpp_shr1(q[0]);
            const float dv    = (pg - p[0]) + (ql - q[0]);
            const float un    = fmaf(-Bq_, dv, fmaf(Ac_, u[0], bf[0]));
            ub[0] = 2.f * un - u[0];
            u[0]  = un;
            if (pub) xb[pb ^ 1][w + 1][0][lane] = ub[0];
        }
        {   // i = RPW-1
            const float ql    = dpp_shr1(q[RPW - 1]);
            const float dv    = (p[RPW - 2] - p[RPW - 1]) + (ql - q[RPW - 1]);
            const float un    = fmaf(-Bq_, dv, fmaf(Ac_, u[RPW - 1], bf[RPW - 1]));
            ub[RPW - 1] = 2.f * un - u[RPW - 1];
            u[RPW - 1]  = un;
            if (pub) xb[pb ^ 1][w + 1][1][lane] = ub[RPW - 1];
        }
        #pragma unroll
        for (int i = 1; i < RPW - 1; ++i) {
            const float ql    = dpp_shr1(q[i]);
            const float dv    = (p[i - 1] - p[i]) + (ql - q[i]);
            const float un    = fmaf(-Bq_, dv, fmaf(Ac_, u[i], bf[i]));
            ub[i] = 2.f * un - u[i];
            u[i]  = un;
        }
        if (pub) __syncthreads();
    }

    // ---------------- store phase (interior only, image-clipped) ----------------
    const int istart = (HLc - w * RPW > 0) ? (HLc - w * RPW) : 0;
    const int iend_  = (HLc + RIr - w * RPW < RPW) ? (HLc + RIr - w * RPW) : RPW;
    const int cst = tc * RIc;
    const int cen = (cst + RIc < 256) ? (cst + RIc) : 256;
    const bool cin = (gj >= cst) && (gj < cen);

    #pragma unroll
    for (int i = 0; i < RPW; ++i) {
        const int row = fr + i;
        if (cin && i >= istart && i < iend_ && (unsigned)row < 256u) {
            fin_out[boff + (row << 8) + gj] = u[i];
        }
    }
}

extern "C" void kernel_launch(void* const* d_in, const int* in_sizes, int n_in,
                              void* d_out, int out_size, void* d_ws, size_t ws_size,
                              hipStream_t stream)
{
    const float* f   = (const float*)d_in[0];
    const float* lam = (const float*)d_in[1];

    dim3 grid(7, 8, 8);      // col-tiles x row-tiles x batch = 448 blocks
    dim3 blkd(NW * 64);      // 512 threads = 8 waves

    tv_one<<<grid, blkd, 0, stream>>>(f, lam, (float*)d_out);
}